// Round 16
// baseline (153.872 us; speedup 1.0000x reference)
//
#include <hip/hip_runtime.h>
#include <hip/hip_bf16.h>

// GMM log-likelihood, N=65536, K=32, F=128.
// R10 structure + TRIANGULAR COMPACTION: precisions_chol is lower-triangular,
// so fragment chunk (g-tile q, f-chunk s) is nonzero only for s >= 2q ->
// 20 of 32 chunks per component (62.5% of MFMA/ds_read/staging work).
// Wave (p,nq): p=0 owns g-tiles {0,3} (8+2 frags), p=1 owns {1,2} (6+4) --
// balanced 10 frags -> 20 MFMAs per comp per wave. Pairwise cross-wave
// combine with partner wid^1 (p^1 holds the complementary g-tiles).
// v-trick mean fold (xv in regs); zc C-operand; 1 barrier/comp (R10 proven).
// Registers ~210/256 at 2 waves/SIMD: xf[2][8]=64, fr[10]=40, acc 64, xv 16.

#define NPTS 65536
#define KC 32
#define FD 128
#define SLABB 20480  // 20 chunks * 64 lanes * 16 B per component (triangular)

typedef __attribute__((ext_vector_type(8))) short short8;
typedef __attribute__((ext_vector_type(8))) unsigned short ushort8;
typedef __attribute__((ext_vector_type(16))) float f32x16;

#define MFMA(A, B, C) __builtin_amdgcn_mfma_f32_32x32x16_bf16((A), (B), (C), 0, 0, 0)

static __device__ __forceinline__ unsigned short f2bf(float f) {
  unsigned int u = __float_as_uint(f);
  u += 0x7FFFu + ((u >> 16) & 1u);  // RNE
  return (unsigned short)(u >> 16);
}

static __device__ __forceinline__ void gll(const unsigned char* g, unsigned char* l) {
  __builtin_amdgcn_global_load_lds((const __attribute__((address_space(1))) void*)g,
                                   (__attribute__((address_space(3))) void*)l, 16, 0, 0);
}

// --- prep12: fused. smp[g] = mu_k @ P_k[:,g]; v[k][f] = P_k[f,:] @ smp;
//     ck3[k] = log w + logdet - 0.5*(F*log2pi + sum_g smp^2) ---
__global__ void prep12(const float* __restrict__ means, const float* __restrict__ P,
                       const float* __restrict__ w, float* __restrict__ v,
                       float* __restrict__ ck3) {
  int k = blockIdx.x, g = threadIdx.x;  // 32 x 128
  const float* Pk = P + k * FD * FD;
  float acc = 0.f;
  for (int f = 0; f < FD; ++f) acc = fmaf(means[k * FD + f], Pk[f * FD + g], acc);
  __shared__ float smp[FD], r1[FD], r2[FD];
  smp[g] = acc;
  r1[g] = logf(Pk[g * FD + g]);
  r2[g] = acc * acc;
  __syncthreads();
  const float* Pr = Pk + g * FD;
  float a2 = 0.f;
  for (int j = 0; j < FD; ++j) a2 = fmaf(Pr[j], smp[j], a2);
  v[k * FD + g] = a2;
  for (int off = 64; off; off >>= 1) {
    if (g < off) { r1[g] += r1[g + off]; r2[g] += r2[g + off]; }
    __syncthreads();
  }
  if (g == 0)
    ck3[k] = logf(w[k]) + r1[0] - 0.5f * ((float)FD * 1.8378770664093453f + r2[0]);
}

// --- prep3: xv mini-slab (8 KB): A'[row k][f] = v[k][f], frag-major ---
__global__ void prep3(const float* __restrict__ v, unsigned char* __restrict__ Ximg) {
  int id = blockIdx.x * 256 + threadIdx.x;  // 0..511 chunks
  int l = id & 63, s = id >> 6;
  int r = l & 31, f0 = 16 * s + 8 * (l >> 5);
  ushort8 o;
#pragma unroll
  for (int j = 0; j < 8; ++j) o[j] = f2bf(v[r * FD + f0 + j]);
  *(ushort8*)(Ximg + (size_t)id * 16) = o;
}

// --- prep4: compacted triangular frag-major bf16 A image.
// Per k: 20 chunks c. c<8: (q=0,s=c); c<10: (q=3,s=c-2); c<16: (q=1,s=c-8);
// else (q=2,s=c-12). Wave p=0 reads c=0..9 (tiles 0,3); p=1 reads c=10..19.
// lane l: g = 32q + (l&31), f = 16s + 8*(l>>5) + j.
__global__ void prep4(const float* __restrict__ P, unsigned char* __restrict__ Aimg) {
  int id = blockIdx.x * 256 + threadIdx.x;  // 0..40959
  int l = id & 63;
  int c = (id >> 6) % 20;
  int k = id / 1280;
  int q, s;
  if (c < 8)       { q = 0; s = c; }
  else if (c < 10) { q = 3; s = c - 2; }
  else if (c < 16) { q = 1; s = c - 8; }
  else             { q = 2; s = c - 12; }
  int g = q * 32 + (l & 31);
  int f0 = 16 * s + 8 * (l >> 5);
  ushort8 o;
#pragma unroll
  for (int j = 0; j < 8; ++j) o[j] = f2bf(P[k * 16384 + (f0 + j) * 128 + g]);
  *(ushort8*)(Aimg + (size_t)id * 16) = o;
}

// --- main ---
__global__ __launch_bounds__(256, 2) void gmm_main(const float* __restrict__ x,
                                                   const unsigned char* __restrict__ Aimg,
                                                   const unsigned char* __restrict__ Ximg,
                                                   const float* __restrict__ ck3,
                                                   float* __restrict__ out) {
  __shared__ __align__(16) unsigned char abuf[2 * SLABB];  // 40 KB
  __shared__ __align__(16) float xch[2][4][32];
  __shared__ float ck[KC];
  const int tid = threadIdx.x;
  const int wid = tid >> 6;
  const int lane = tid & 63;
  const int half = lane >> 5;
  const int ln = lane & 31;
  const int p = wid & 1;    // g-tile pair: p=0 -> {0,3}, p=1 -> {1,2}
  const int nq = wid >> 1;  // n-half this wave owns (64 x-rows, tiles t=0,1)
  const int nbase = blockIdx.x * 128;

  if (tid < KC) ck[tid] = ck3[tid];

  // prologue staging: Ximg (8 KB) -> buf1, slab0 -> buf0 (5 gll/wave)
  {
    const unsigned char* gx = Ximg + wid * 2048 + lane * 16;
    unsigned char* lx = abuf + SLABB + wid * 2048;
    gll(gx, lx);
    gll(gx + 1024, lx + 1024);
    const unsigned char* gs = Aimg + wid * 5120 + lane * 16;
    unsigned char* ls = abuf + wid * 5120;
#pragma unroll
    for (int i = 0; i < 5; ++i) gll(gs + i * 1024, ls + i * 1024);
  }

  // B fragments: this wave's 64 x-rows (2 n-tiles), resident all kernel.
  // xf[t][s][j] = x[nbase + nq*64 + t*32 + ln][16s + 8*half + j]  (64 VGPR)
  short8 xf[2][8];
#pragma unroll
  for (int t = 0; t < 2; ++t) {
    const float* xr = x + (size_t)(nbase + nq * 64 + t * 32 + ln) * FD + 8 * half;
#pragma unroll
    for (int s = 0; s < 8; ++s) {
      const float4 a = *(const float4*)(xr + 16 * s);
      const float4 b = *(const float4*)(xr + 16 * s + 4);
      short8 f;
      f[0] = (short)f2bf(a.x); f[1] = (short)f2bf(a.y);
      f[2] = (short)f2bf(a.z); f[3] = (short)f2bf(a.w);
      f[4] = (short)f2bf(b.x); f[5] = (short)f2bf(b.y);
      f[6] = (short)f2bf(b.z); f[7] = (short)f2bf(b.w);
      xf[t][s] = f;
    }
  }

  f32x16 zc;  // persistent zero C-operand
#pragma unroll
  for (int i = 0; i < 16; ++i) zc[i] = 0.f;

  asm volatile("s_waitcnt vmcnt(0)" ::: "memory");
  __syncthreads();

  // xv[n,k] mini-GEMM for the n-tile this wave finalizes (t == p):
  // row k = (i&3)+8*(i>>2)+4*half, col n = nbase + nq*64 + p*32 + ln
  f32x16 xv;
  {
    const unsigned char* xb = abuf + SLABB + lane * 16;
    {
      const short8 fx = *(const short8*)xb;
      xv = MFMA(fx, xf[p][0], zc);
    }
#pragma unroll
    for (int s = 1; s < 8; ++s) {
      const short8 fx = *(const short8*)(xb + s * 1024);
      xv = MFMA(fx, xf[p][s], xv);
    }
  }
  __syncthreads();  // Ximg consumed; buf1 free for slab1 staging

  float m = -__builtin_inff(), ssum = 0.f;

  for (int k = 0; k < KC; ++k) {
    const int RB = (k & 1) * SLABB;
    const int WB = SLABB - RB;
    const int ph = k & 1;
    // this wave's 10 triangular frags (conflict-free, consecutive chunks)
    const unsigned char* rb = abuf + RB + p * 10240 + lane * 16;
    short8 fr[10];
#pragma unroll
    for (int i = 0; i < 10; ++i) fr[i] = *(const short8*)(rb + i * 1024);
    if (k + 1 < KC) {  // stage slab k+1 (5 gll per wave)
      const unsigned char* gs = Aimg + (size_t)(k + 1) * SLABB + wid * 5120 + lane * 16;
      unsigned char* ls = abuf + WB + wid * 5120;
#pragma unroll
      for (int i = 0; i < 5; ++i) gll(gs + i * 1024, ls + i * 1024);
    }
    f32x16 a00, a01, a10, a11;
    __builtin_amdgcn_s_setprio(1);
    if (p == 0) {
      // g-tile 0: full K (s=0..7); g-tile 3: s=6,7
      a00 = MFMA(fr[0], xf[0][0], zc);
      a01 = MFMA(fr[0], xf[1][0], zc);
#pragma unroll
      for (int s = 1; s < 8; ++s) {
        a00 = MFMA(fr[s], xf[0][s], a00);
        a01 = MFMA(fr[s], xf[1][s], a01);
      }
      a10 = MFMA(fr[8], xf[0][6], zc);
      a11 = MFMA(fr[8], xf[1][6], zc);
      a10 = MFMA(fr[9], xf[0][7], a10);
      a11 = MFMA(fr[9], xf[1][7], a11);
    } else {
      // g-tile 1: s=2..7; g-tile 2: s=4..7
      a00 = MFMA(fr[0], xf[0][2], zc);
      a01 = MFMA(fr[0], xf[1][2], zc);
#pragma unroll
      for (int s = 1; s < 6; ++s) {
        a00 = MFMA(fr[s], xf[0][s + 2], a00);
        a01 = MFMA(fr[s], xf[1][s + 2], a01);
      }
      a10 = MFMA(fr[6], xf[0][4], zc);
      a11 = MFMA(fr[6], xf[1][4], zc);
#pragma unroll
      for (int j = 1; j < 4; ++j) {
        a10 = MFMA(fr[6 + j], xf[0][4 + j], a10);
        a11 = MFMA(fr[6 + j], xf[1][4 + j], a11);
      }
    }
    __builtin_amdgcn_s_setprio(0);
    // epilogue: per-n-tile squares over this wave's two g-tiles (64 g)
    float q0a = 0.f, q0b = 0.f, q1a = 0.f, q1b = 0.f;
#pragma unroll
    for (int i = 0; i < 16; ++i) {
      q0a = fmaf(a00[i], a00[i], q0a);
      q0b = fmaf(a10[i], a10[i], q0b);
      q1a = fmaf(a01[i], a01[i], q1a);
      q1b = fmaf(a11[i], a11[i], q1b);
    }
    float q0 = q0a + q0b, q1 = q1a + q1b;
    q0 += __shfl_xor(q0, 32, 64);  // both halves hold the 64-g pair partials
    q1 += __shfl_xor(q1, 32, 64);
    float sown = p ? q1 : q0;  // n-tile this wave finalizes (t == p)
    float soth = p ? q0 : q1;  // n-tile the partner (wid^1) finalizes
    if (half == 0) xch[ph][wid ^ 1][ln] = soth;
    if (k + 1 < KC) asm volatile("s_waitcnt vmcnt(0)" ::: "memory");
    __syncthreads();  // xch visibility + staging handoff (one barrier/comp)
    float sfull = sown + xch[ph][wid][ln];  // + partner's 64 g -> full 128-g
    // -2 * x.v_k, made half-uniform with one shfl
    const int owner = (k >> 2) & 1;
    const int idx = (k & 3) | ((k >> 3) << 2);
    float tx = (half == owner) ? xv[idx] : 0.f;
    tx += __shfl_xor(tx, 32, 64);
    sfull = fmaf(-2.f, tx, sfull);
    float vv = ck[k] - 0.5f * sfull;
    float nm = fmaxf(m, vv);
    ssum = ssum * __expf(m - nm) + __expf(vv - nm);
    m = nm;
  }

  if (half == 0) out[nbase + nq * 64 + p * 32 + ln] = m + logf(ssum);
}

extern "C" void kernel_launch(void* const* d_in, const int* in_sizes, int n_in,
                              void* d_out, int out_size, void* d_ws, size_t ws_size,
                              hipStream_t stream) {
  const float* x = (const float*)d_in[0];
  const float* means = (const float*)d_in[1];
  const float* P = (const float*)d_in[2];
  const float* w = (const float*)d_in[3];
  float* out = (float*)d_out;

  unsigned char* ws = (unsigned char*)d_ws;
  unsigned char* Aimg = ws;                      // 32 * 20480 = 655360 B
  unsigned char* Ximg = ws + 655360;             // 8192 B
  float* v = (float*)(ws + 655360 + 8192);       // 16384 B
  float* ck3 = (float*)(ws + 655360 + 24576);    // 128 B

  prep12<<<32, 128, 0, stream>>>(means, P, w, v, ck3);
  prep3<<<2, 256, 0, stream>>>(v, Ximg);
  prep4<<<160, 256, 0, stream>>>(P, Aimg);
  gmm_main<<<NPTS / 128, 256, 0, stream>>>(x, Aimg, Ximg, ck3, out);
}

// Round 17
// 63.393 us; speedup vs baseline: 2.4273x; 2.4273x over previous
//
#include <hip/hip_runtime.h>
#include <hip/hip_bf16.h>

// GMM log-likelihood, N=65536, K=32, F=128.
// R10 structure + triangular compaction (s >= 2q -> 20 of 32 chunks/comp).
// Wave (p,nq): p=0 owns g-tiles {0,3} (8+2 frags), p=1 owns {1,2} (6+4) --
// balanced 10 frags -> 20 MFMAs per comp per wave. Pairwise cross-wave
// combine with partner wid^1. v-trick mean fold; zc C-operand; 1 barrier/comp.
// RULE-20 FIX vs R16: xv prologue selects xf bank via ternary (register
// cndmask), never xf[p][s] runtime indexing (which forced xf to scratch and
// caused R16's 33 MB spill traffic).

#define NPTS 65536
#define KC 32
#define FD 128
#define SLABB 20480  // 20 chunks * 64 lanes * 16 B per component (triangular)

typedef __attribute__((ext_vector_type(8))) short short8;
typedef __attribute__((ext_vector_type(8))) unsigned short ushort8;
typedef __attribute__((ext_vector_type(16))) float f32x16;

#define MFMA(A, B, C) __builtin_amdgcn_mfma_f32_32x32x16_bf16((A), (B), (C), 0, 0, 0)

static __device__ __forceinline__ unsigned short f2bf(float f) {
  unsigned int u = __float_as_uint(f);
  u += 0x7FFFu + ((u >> 16) & 1u);  // RNE
  return (unsigned short)(u >> 16);
}

static __device__ __forceinline__ void gll(const unsigned char* g, unsigned char* l) {
  __builtin_amdgcn_global_load_lds((const __attribute__((address_space(1))) void*)g,
                                   (__attribute__((address_space(3))) void*)l, 16, 0, 0);
}

// --- prep12: fused. smp[g] = mu_k @ P_k[:,g]; v[k][f] = P_k[f,:] @ smp;
//     ck3[k] = log w + logdet - 0.5*(F*log2pi + sum_g smp^2) ---
__global__ void prep12(const float* __restrict__ means, const float* __restrict__ P,
                       const float* __restrict__ w, float* __restrict__ v,
                       float* __restrict__ ck3) {
  int k = blockIdx.x, g = threadIdx.x;  // 32 x 128
  const float* Pk = P + k * FD * FD;
  float acc = 0.f;
  for (int f = 0; f < FD; ++f) acc = fmaf(means[k * FD + f], Pk[f * FD + g], acc);
  __shared__ float smp[FD], r1[FD], r2[FD];
  smp[g] = acc;
  r1[g] = logf(Pk[g * FD + g]);
  r2[g] = acc * acc;
  __syncthreads();
  const float* Pr = Pk + g * FD;
  float a2 = 0.f;
  for (int j = 0; j < FD; ++j) a2 = fmaf(Pr[j], smp[j], a2);
  v[k * FD + g] = a2;
  for (int off = 64; off; off >>= 1) {
    if (g < off) { r1[g] += r1[g + off]; r2[g] += r2[g + off]; }
    __syncthreads();
  }
  if (g == 0)
    ck3[k] = logf(w[k]) + r1[0] - 0.5f * ((float)FD * 1.8378770664093453f + r2[0]);
}

// --- prep3: xv mini-slab (8 KB): A'[row k][f] = v[k][f], frag-major ---
__global__ void prep3(const float* __restrict__ v, unsigned char* __restrict__ Ximg) {
  int id = blockIdx.x * 256 + threadIdx.x;  // 0..511 chunks
  int l = id & 63, s = id >> 6;
  int r = l & 31, f0 = 16 * s + 8 * (l >> 5);
  ushort8 o;
#pragma unroll
  for (int j = 0; j < 8; ++j) o[j] = f2bf(v[r * FD + f0 + j]);
  *(ushort8*)(Ximg + (size_t)id * 16) = o;
}

// --- prep4: compacted triangular frag-major bf16 A image.
// Per k: 20 chunks c. c<8: (q=0,s=c); c<10: (q=3,s=c-2); c<16: (q=1,s=c-8);
// else (q=2,s=c-12). Wave p=0 reads c=0..9 (tiles 0,3); p=1 reads c=10..19.
// lane l: g = 32q + (l&31), f = 16s + 8*(l>>5) + j.
__global__ void prep4(const float* __restrict__ P, unsigned char* __restrict__ Aimg) {
  int id = blockIdx.x * 256 + threadIdx.x;  // 0..40959
  int l = id & 63;
  int c = (id >> 6) % 20;
  int k = id / 1280;
  int q, s;
  if (c < 8)       { q = 0; s = c; }
  else if (c < 10) { q = 3; s = c - 2; }
  else if (c < 16) { q = 1; s = c - 8; }
  else             { q = 2; s = c - 12; }
  int g = q * 32 + (l & 31);
  int f0 = 16 * s + 8 * (l >> 5);
  ushort8 o;
#pragma unroll
  for (int j = 0; j < 8; ++j) o[j] = f2bf(P[k * 16384 + (f0 + j) * 128 + g]);
  *(ushort8*)(Aimg + (size_t)id * 16) = o;
}

// --- main ---
__global__ __launch_bounds__(256, 2) void gmm_main(const float* __restrict__ x,
                                                   const unsigned char* __restrict__ Aimg,
                                                   const unsigned char* __restrict__ Ximg,
                                                   const float* __restrict__ ck3,
                                                   float* __restrict__ out) {
  __shared__ __align__(16) unsigned char abuf[2 * SLABB];  // 40 KB
  __shared__ __align__(16) float xch[2][4][32];
  __shared__ float ck[KC];
  const int tid = threadIdx.x;
  const int wid = tid >> 6;
  const int lane = tid & 63;
  const int half = lane >> 5;
  const int ln = lane & 31;
  const int p = wid & 1;    // g-tile pair: p=0 -> {0,3}, p=1 -> {1,2}
  const int nq = wid >> 1;  // n-half this wave owns (64 x-rows, tiles t=0,1)
  const int nbase = blockIdx.x * 128;

  if (tid < KC) ck[tid] = ck3[tid];

  // prologue staging: Ximg (8 KB) -> buf1, slab0 -> buf0 (5 gll/wave)
  {
    const unsigned char* gx = Ximg + wid * 2048 + lane * 16;
    unsigned char* lx = abuf + SLABB + wid * 2048;
    gll(gx, lx);
    gll(gx + 1024, lx + 1024);
    const unsigned char* gs = Aimg + wid * 5120 + lane * 16;
    unsigned char* ls = abuf + wid * 5120;
#pragma unroll
    for (int i = 0; i < 5; ++i) gll(gs + i * 1024, ls + i * 1024);
  }

  // B fragments: this wave's 64 x-rows (2 n-tiles), resident all kernel.
  // xf[t][s][j] = x[nbase + nq*64 + t*32 + ln][16s + 8*half + j]  (64 VGPR)
  short8 xf[2][8];
#pragma unroll
  for (int t = 0; t < 2; ++t) {
    const float* xr = x + (size_t)(nbase + nq * 64 + t * 32 + ln) * FD + 8 * half;
#pragma unroll
    for (int s = 0; s < 8; ++s) {
      const float4 a = *(const float4*)(xr + 16 * s);
      const float4 b = *(const float4*)(xr + 16 * s + 4);
      short8 f;
      f[0] = (short)f2bf(a.x); f[1] = (short)f2bf(a.y);
      f[2] = (short)f2bf(a.z); f[3] = (short)f2bf(a.w);
      f[4] = (short)f2bf(b.x); f[5] = (short)f2bf(b.y);
      f[6] = (short)f2bf(b.z); f[7] = (short)f2bf(b.w);
      xf[t][s] = f;
    }
  }

  f32x16 zc;  // persistent zero C-operand
#pragma unroll
  for (int i = 0; i < 16; ++i) zc[i] = 0.f;

  asm volatile("s_waitcnt vmcnt(0)" ::: "memory");
  __syncthreads();

  // xv[n,k] mini-GEMM for the n-tile this wave finalizes (t == p):
  // row k = (i&3)+8*(i>>2)+4*half, col n = nbase + nq*64 + p*32 + ln
  // NOTE: ternary register-select, never xf[p][s] (rule-20).
  f32x16 xv;
  {
    const unsigned char* xb = abuf + SLABB + lane * 16;
    {
      const short8 fx = *(const short8*)xb;
      xv = MFMA(fx, p ? xf[1][0] : xf[0][0], zc);
    }
#pragma unroll
    for (int s = 1; s < 8; ++s) {
      const short8 fx = *(const short8*)(xb + s * 1024);
      xv = MFMA(fx, p ? xf[1][s] : xf[0][s], xv);
    }
  }
  __syncthreads();  // Ximg consumed; buf1 free for slab1 staging

  float m = -__builtin_inff(), ssum = 0.f;

  for (int k = 0; k < KC; ++k) {
    const int RB = (k & 1) * SLABB;
    const int WB = SLABB - RB;
    const int ph = k & 1;
    // this wave's 10 triangular frags (consecutive chunks, conflict-free)
    const unsigned char* rb = abuf + RB + p * 10240 + lane * 16;
    short8 fr[10];
#pragma unroll
    for (int i = 0; i < 10; ++i) fr[i] = *(const short8*)(rb + i * 1024);
    if (k + 1 < KC) {  // stage slab k+1 (5 gll per wave)
      const unsigned char* gs = Aimg + (size_t)(k + 1) * SLABB + wid * 5120 + lane * 16;
      unsigned char* ls = abuf + WB + wid * 5120;
#pragma unroll
      for (int i = 0; i < 5; ++i) gll(gs + i * 1024, ls + i * 1024);
    }
    f32x16 a00, a01, a10, a11;
    __builtin_amdgcn_s_setprio(1);
    if (p == 0) {
      // g-tile 0: full K (s=0..7); g-tile 3: s=6,7
      a00 = MFMA(fr[0], xf[0][0], zc);
      a01 = MFMA(fr[0], xf[1][0], zc);
#pragma unroll
      for (int s = 1; s < 8; ++s) {
        a00 = MFMA(fr[s], xf[0][s], a00);
        a01 = MFMA(fr[s], xf[1][s], a01);
      }
      a10 = MFMA(fr[8], xf[0][6], zc);
      a11 = MFMA(fr[8], xf[1][6], zc);
      a10 = MFMA(fr[9], xf[0][7], a10);
      a11 = MFMA(fr[9], xf[1][7], a11);
    } else {
      // g-tile 1: s=2..7; g-tile 2: s=4..7
      a00 = MFMA(fr[0], xf[0][2], zc);
      a01 = MFMA(fr[0], xf[1][2], zc);
#pragma unroll
      for (int s = 1; s < 6; ++s) {
        a00 = MFMA(fr[s], xf[0][s + 2], a00);
        a01 = MFMA(fr[s], xf[1][s + 2], a01);
      }
      a10 = MFMA(fr[6], xf[0][4], zc);
      a11 = MFMA(fr[6], xf[1][4], zc);
#pragma unroll
      for (int j = 1; j < 4; ++j) {
        a10 = MFMA(fr[6 + j], xf[0][4 + j], a10);
        a11 = MFMA(fr[6 + j], xf[1][4 + j], a11);
      }
    }
    __builtin_amdgcn_s_setprio(0);
    // epilogue: per-n-tile squares over this wave's two g-tiles (64 g)
    float q0a = 0.f, q0b = 0.f, q1a = 0.f, q1b = 0.f;
#pragma unroll
    for (int i = 0; i < 16; ++i) {
      q0a = fmaf(a00[i], a00[i], q0a);
      q0b = fmaf(a10[i], a10[i], q0b);
      q1a = fmaf(a01[i], a01[i], q1a);
      q1b = fmaf(a11[i], a11[i], q1b);
    }
    float q0 = q0a + q0b, q1 = q1a + q1b;
    q0 += __shfl_xor(q0, 32, 64);  // both halves hold the 64-g pair partials
    q1 += __shfl_xor(q1, 32, 64);
    float sown = p ? q1 : q0;  // n-tile this wave finalizes (t == p)
    float soth = p ? q0 : q1;  // n-tile the partner (wid^1) finalizes
    if (half == 0) xch[ph][wid ^ 1][ln] = soth;
    if (k + 1 < KC) asm volatile("s_waitcnt vmcnt(0)" ::: "memory");
    __syncthreads();  // xch visibility + staging handoff (one barrier/comp)
    float sfull = sown + xch[ph][wid][ln];  // + partner's 64 g -> full 128-g
    // -2 * x.v_k, made half-uniform with one shfl
    const int owner = (k >> 2) & 1;
    const int idx = (k & 3) | ((k >> 3) << 2);
    float tx = (half == owner) ? xv[idx] : 0.f;
    tx += __shfl_xor(tx, 32, 64);
    sfull = fmaf(-2.f, tx, sfull);
    float vv = ck[k] - 0.5f * sfull;
    float nm = fmaxf(m, vv);
    ssum = ssum * __expf(m - nm) + __expf(vv - nm);
    m = nm;
  }

  if (half == 0) out[nbase + nq * 64 + p * 32 + ln] = m + logf(ssum);
}

extern "C" void kernel_launch(void* const* d_in, const int* in_sizes, int n_in,
                              void* d_out, int out_size, void* d_ws, size_t ws_size,
                              hipStream_t stream) {
  const float* x = (const float*)d_in[0];
  const float* means = (const float*)d_in[1];
  const float* P = (const float*)d_in[2];
  const float* w = (const float*)d_in[3];
  float* out = (float*)d_out;

  unsigned char* ws = (unsigned char*)d_ws;
  unsigned char* Aimg = ws;                      // 32 * 20480 = 655360 B
  unsigned char* Ximg = ws + 655360;             // 8192 B
  float* v = (float*)(ws + 655360 + 8192);       // 16384 B
  float* ck3 = (float*)(ws + 655360 + 24576);    // 128 B

  prep12<<<32, 128, 0, stream>>>(means, P, w, v, ck3);
  prep3<<<2, 256, 0, stream>>>(v, Ximg);
  prep4<<<160, 256, 0, stream>>>(P, Aimg);
  gmm_main<<<NPTS / 128, 256, 0, stream>>>(x, Aimg, Ximg, ck3, out);
}